// Round 6
// baseline (529.610 us; speedup 1.0000x reference)
//
#include <hip/hip_runtime.h>
#include <hip/hip_bf16.h>

// Problem constants
#define B_   64
#define C_   3129
#define K_   10
#define DF_  768
#define F_   676      // 26*26
#define DW_  300
#define DWP_ 320      // DW_ padded to multiple of 64 (MFMA K-tile)
#define DT_  1024
#define NSEG 4        // o_bap f-segments: 676 = 4*169
#define FSEG 169

typedef __attribute__((ext_vector_type(8))) short short8;   // 8 bf16
typedef __attribute__((ext_vector_type(4))) float floatx4;  // 4 fp32

// async 16B global -> LDS (wave-uniform LDS base + lane*16)
__device__ __forceinline__ void gload_lds16(const void* g, void* l) {
    __builtin_amdgcn_global_load_lds(
        (const __attribute__((address_space(1))) void*)g,
        (__attribute__((address_space(3))) void*)l, 16, 0, 0);
}

// ---------------------------------------------------------------------------
// 1. fused: per-b top-k (exact lax.top_k order) + class embedding (bf16,
//    K-padded to DWP_ with zeros)
__global__ void topk_emb_kernel(const float* __restrict__ logits,
                                const int* __restrict__ indices_table,
                                const float* __restrict__ word2vec,
                                int* __restrict__ topk_idx,
                                __hip_bfloat16* __restrict__ emb) {
    __shared__ float vals[C_];
    __shared__ float red_v[256];
    __shared__ int   red_i[256];
    __shared__ int   sel_idx[K_];
    int b = blockIdx.x;
    int tid = threadIdx.x;
    for (int i = tid; i < C_; i += 256) vals[i] = logits[(size_t)b * C_ + i];
    __syncthreads();
    for (int sel = 0; sel < K_; ++sel) {
        float bv = -INFINITY; int bi = 0x7fffffff;
        for (int i = tid; i < C_; i += 256) {
            float v = vals[i];
            if (v > bv) { bv = v; bi = i; }   // strict > keeps lowest index
        }
        red_v[tid] = bv; red_i[tid] = bi;
        __syncthreads();
        for (int s = 128; s > 0; s >>= 1) {
            if (tid < s) {
                float ov = red_v[tid + s]; int oi = red_i[tid + s];
                if (ov > red_v[tid] || (ov == red_v[tid] && oi < red_i[tid])) {
                    red_v[tid] = ov; red_i[tid] = oi;
                }
            }
            __syncthreads();
        }
        if (tid == 0) {
            topk_idx[b * K_ + sel] = red_i[0];
            sel_idx[sel] = red_i[0];
            vals[red_i[0]] = -INFINITY;
        }
        __syncthreads();
    }
    // phase 2: emb for this b (K_ * DWP_ = 3200 elems)
    for (int idx = tid; idx < K_ * DWP_; idx += 256) {
        int j = idx % DWP_;
        int k = idx / DWP_;
        float s = 0.f;
        if (j < DW_) {
            int cls = sel_idx[k];
            const int* tbl = indices_table + (size_t)cls * 4;
            #pragma unroll
            for (int i = 0; i < 4; ++i) s += word2vec[(size_t)tbl[i] * DW_ + j];
            s *= 0.25f;
        }
        emb[((size_t)b * K_ + k) * DWP_ + j] = (__hip_bfloat16)s;
    }
}

// ---------------------------------------------------------------------------
// Transpose body: src[R][Cc] fp32 -> dst[Cc][Rp] bf16, zero-padded rows >= R.
__device__ __forceinline__ void tp_body(const float* __restrict__ s,
                                        __hip_bfloat16* __restrict__ d,
                                        int R, int Cc, int Rp, int c0, int r0) {
    __shared__ float tile[64][65];
    int t = threadIdx.x;
    int cl = (t & 15) * 4;
    int rl = t >> 4;
    #pragma unroll
    for (int i = 0; i < 4; ++i) {
        int r = rl + i * 16;
        float4 v = make_float4(0.f, 0.f, 0.f, 0.f);
        if (r0 + r < R && c0 + cl < Cc)
            v = *(const float4*)(s + (size_t)(r0 + r) * Cc + c0 + cl);
        tile[r][cl + 0] = v.x; tile[r][cl + 1] = v.y;
        tile[r][cl + 2] = v.z; tile[r][cl + 3] = v.w;
    }
    __syncthreads();
    int cw = t >> 2;
    int r4 = (t & 3) * 16;
    if (c0 + cw < Cc) {
        __align__(16) __hip_bfloat16 buf[16];
        #pragma unroll
        for (int j = 0; j < 16; ++j) buf[j] = (__hip_bfloat16)tile[r4 + j][cw];
        float4* dp = (float4*)(d + (size_t)(c0 + cw) * Rp + r0 + r4);
        dp[0] = *(float4*)&buf[0];
        dp[1] = *(float4*)&buf[8];
    }
}

// weight tile dispatch: W_emb 80 | W_cls 256 | W_v 192 | W_bap 256 = 784
__device__ __forceinline__ void tp_weights(int id,
        const float* Wemb, __hip_bfloat16* WembT,
        const float* Wcls, __hip_bfloat16* WclsT,
        const float* Wv,   __hip_bfloat16* WvT,
        const float* Wbap, __hip_bfloat16* WbapT) {
    const float* s; __hip_bfloat16* d; int R, Rp;
    if (id < 80)       { s = Wemb; d = WembT; R = DW_;  Rp = DWP_; }
    else if (id < 336) { s = Wcls; d = WclsT; R = DT_;  Rp = DT_;  id -= 80;  }
    else if (id < 528) { s = Wv;   d = WvT;   R = DF_;  Rp = DF_;  id -= 336; }
    else               { s = Wbap; d = WbapT; R = DT_;  Rp = DT_;  id -= 528; }
    int bx = id & 15;        // Cc = 1024 -> 16 col tiles for all mats
    int by = id >> 4;
    tp_body(s, d, R, DT_, Rp, bx * 64, by * 64);
}

__global__ __launch_bounds__(256)
void transpose_weights(const float* __restrict__ Wemb, __hip_bfloat16* __restrict__ WembT,
                       const float* __restrict__ Wcls, __hip_bfloat16* __restrict__ WclsT,
                       const float* __restrict__ Wv,   __hip_bfloat16* __restrict__ WvT,
                       const float* __restrict__ Wbap, __hip_bfloat16* __restrict__ WbapT) {
    tp_weights(blockIdx.x, Wemb, WembT, Wcls, WclsT, Wv, WvT, Wbap, WbapT);
}

// ftm transpose (z-batched), chunked path
__global__ __launch_bounds__(256)
void transpose_ftm(const float* __restrict__ src, __hip_bfloat16* __restrict__ dst) {
    tp_body(src + (size_t)blockIdx.z * DF_ * F_,
            dst + (size_t)blockIdx.z * F_ * DF_,
            DF_, F_, DF_, blockIdx.x * 64, blockIdx.y * 64);
}

// single-pass path: all weights + all 64 ftm batches in ONE dispatch
// grid = 784 + 64*132 = 9232  (ftm: 11 f-tiles x 12 k-tiles per batch)
__global__ __launch_bounds__(256)
void transpose_all(const float* __restrict__ Wemb, __hip_bfloat16* __restrict__ WembT,
                   const float* __restrict__ Wcls, __hip_bfloat16* __restrict__ WclsT,
                   const float* __restrict__ Wv,   __hip_bfloat16* __restrict__ WvT,
                   const float* __restrict__ Wbap, __hip_bfloat16* __restrict__ WbapT,
                   const float* __restrict__ ftm,  __hip_bfloat16* __restrict__ ftmT) {
    int id = blockIdx.x;
    if (id < 784) {
        tp_weights(id, Wemb, WembT, Wcls, WclsT, Wv, WvT, Wbap, WbapT);
    } else {
        id -= 784;
        int z = id / 132, rem = id % 132;
        int bx = rem % 11, by = rem / 11;
        tp_body(ftm + (size_t)z * DF_ * F_, ftmT + (size_t)z * F_ * DF_,
                DF_, F_, DF_, bx * 64, by * 64);
    }
}

// ---------------------------------------------------------------------------
// MFMA bf16 GEMM: C[M][N] = act(A[M][Kp] @ Bt[N][Kp]^T + bias)
// 128x128 tile, BK=64, global_load_lds w16 + XOR chunk swizzle, coalesced LDS
// epilogue (OUTBF=1).
// SWZ=1: XCD-slab remap. Requires gridDim.x == 8 (N=1024) and gridDim.y % 8
// == 0 (m-blocks padded; excess blocks exit). Flat id = by*8+bx, HW assigns
// XCD = id%8 = bx round-robin; we give XCD bx a contiguous m-slab with n
// cycling fastest -> A fetched ~once per XCD, B L2-resident.
template <int RELU, int OUTBF, int SWZ>
__global__ __launch_bounds__(256)
void gemm_mfma(const __hip_bfloat16* __restrict__ A,
               const __hip_bfloat16* __restrict__ Bt,
               const float* __restrict__ bias,
               void* __restrict__ Cout, int M, int N, int Kp) {
    int n0, m0;
    if (SWZ) {
        int mblocks = (M + 127) >> 7;
        int slab = gridDim.y >> 3;           // m-tiles per XCD
        int m = (blockIdx.y >> 3) + slab * blockIdx.x;
        if (m >= mblocks) return;
        n0 = (blockIdx.y & 7) * 128;
        m0 = m * 128;
    } else {
        n0 = blockIdx.x * 128;
        m0 = blockIdx.y * 128;
    }
    __shared__ __align__(16) char smem[34816];       // max(As+Bs, C-tile 128x136)
    __hip_bfloat16* As = (__hip_bfloat16*)smem;      // [128][64]
    __hip_bfloat16* Bs = As + 128 * 64;              // [128][64]
    int tid = threadIdx.x;
    int wave = tid >> 6, lane = tid & 63;
    int quad = lane >> 4, l16 = lane & 15;
    int wm = (wave & 1) * 64, wn = (wave >> 1) * 64;

    floatx4 acc[4][4];
    #pragma unroll
    for (int i = 0; i < 4; ++i)
        #pragma unroll
        for (int j = 0; j < 4; ++j)
            acc[i][j] = (floatx4){0.f, 0.f, 0.f, 0.f};

    // staging: group g = wave*4+c covers LDS rows [g*8, g*8+8) (1024 B).
    // lane l: row sub l>>3, LDS chunk q = l&7; global chunk = q ^ rsub.
    int rsub = lane >> 3;
    int gchunk = (lane & 7) ^ rsub;

    int arow[4], brow[4];
    #pragma unroll
    for (int i = 0; i < 4; ++i) {
        arow[i] = wm + i * 16 + l16;
        brow[i] = wn + i * 16 + l16;
    }

    for (int k0 = 0; k0 < Kp; k0 += 64) {
        #pragma unroll
        for (int c = 0; c < 4; ++c) {
            int grp = wave * 4 + c;
            int row = grp * 8 + rsub;
            int ra = m0 + row; if (ra >= M) ra = M - 1;   // clamp: junk unused
            gload_lds16(A + (size_t)ra * Kp + k0 + gchunk * 8, As + grp * 512);
            gload_lds16(Bt + (size_t)(n0 + row) * Kp + k0 + gchunk * 8, Bs + grp * 512);
        }
        __syncthreads();
        #pragma unroll
        for (int ks = 0; ks < 2; ++ks) {
            short8 af[4], bf[4];
            #pragma unroll
            for (int mi = 0; mi < 4; ++mi)
                af[mi] = *(const short8*)&As[arow[mi] * 64 +
                            ((((ks << 2) | quad) ^ (arow[mi] & 7)) << 3)];
            #pragma unroll
            for (int ni = 0; ni < 4; ++ni)
                bf[ni] = *(const short8*)&Bs[brow[ni] * 64 +
                            ((((ks << 2) | quad) ^ (brow[ni] & 7)) << 3)];
            #pragma unroll
            for (int mi = 0; mi < 4; ++mi)
                #pragma unroll
                for (int ni = 0; ni < 4; ++ni)
                    acc[mi][ni] = __builtin_amdgcn_mfma_f32_16x16x32_bf16(
                        af[mi], bf[ni], acc[mi][ni], 0, 0, 0);
        }
        __syncthreads();
    }

    // C/D mapping: col = lane&15, row = quad*4 + reg  [measured m89/m91]
    float bn[4];
    #pragma unroll
    for (int ni = 0; ni < 4; ++ni) bn[ni] = bias[n0 + wn + ni * 16 + l16];

    if (OUTBF) {
        __hip_bfloat16* Cs = (__hip_bfloat16*)smem;
        #pragma unroll
        for (int mi = 0; mi < 4; ++mi)
            #pragma unroll
            for (int rr = 0; rr < 4; ++rr) {
                int row = wm + mi * 16 + quad * 4 + rr;
                #pragma unroll
                for (int ni = 0; ni < 4; ++ni) {
                    float val = acc[mi][ni][rr] + bn[ni];
                    if (RELU) val = fmaxf(val, 0.f);
                    Cs[row * 136 + wn + ni * 16 + l16] = (__hip_bfloat16)val;
                }
            }
        __syncthreads();
        #pragma unroll
        for (int j = 0; j < 8; ++j) {
            int ch = tid + 256 * j;              // 2048 chunks of 16 B
            int row = ch >> 4, c16 = ch & 15;
            int r = m0 + row;
            float4 val = *(const float4*)&Cs[row * 136 + c16 * 8];
            if (r < M)
                *(float4*)((__hip_bfloat16*)Cout + (size_t)r * N + n0 + c16 * 8) = val;
        }
    } else {
        #pragma unroll
        for (int mi = 0; mi < 4; ++mi)
            #pragma unroll
            for (int rr = 0; rr < 4; ++rr) {
                int r = m0 + wm + mi * 16 + quad * 4 + rr;
                if (r < M) {
                    #pragma unroll
                    for (int ni = 0; ni < 4; ++ni) {
                        float val = acc[mi][ni][rr] + bn[ni];
                        if (RELU) val = fmaxf(val, 0.f);
                        ((float*)Cout)[(size_t)r * N + n0 + wn + ni * 16 + l16] = val;
                    }
                }
            }
    }
}

// ---------------------------------------------------------------------------
// 4. s[bc,f,k] = sum_d v[bc,f,d] * cls[b0+bc,k,d]; 2 f per wave
__global__ __launch_bounds__(256)
void attn_s_kernel(const __hip_bfloat16* __restrict__ v_buf,
                   const __hip_bfloat16* __restrict__ cls,
                   float* __restrict__ s_buf, int b0) {
    int tid = threadIdx.x;
    int wave = tid >> 6, lane = tid & 63;
    int bc = blockIdx.y;
    int f0 = blockIdx.x * 8 + wave * 2;     // 85 blocks cover 680 >= 676
    int fa = f0 < F_ ? f0 : F_ - 1;
    int fb = (f0 + 1) < F_ ? f0 + 1 : F_ - 1;
    union U { float4 f4; __hip_bfloat16 h[8]; };
    const float4* va = (const float4*)(v_buf + ((size_t)(bc * F_ + fa)) * DT_ + lane * 16);
    const float4* vb = (const float4*)(v_buf + ((size_t)(bc * F_ + fb)) * DT_ + lane * 16);
    U a0, a1, b0u, b1u;
    a0.f4 = va[0]; a1.f4 = va[1];
    b0u.f4 = vb[0]; b1u.f4 = vb[1];
    float av[16], bv[16];
    #pragma unroll
    for (int i = 0; i < 8; ++i) {
        av[i] = (float)a0.h[i]; av[8 + i] = (float)a1.h[i];
        bv[i] = (float)b0u.h[i]; bv[8 + i] = (float)b1u.h[i];
    }
    const __hip_bfloat16* cp = cls + ((size_t)(b0 + bc) * K_) * DT_ + lane * 16;
    #pragma unroll
    for (int k = 0; k < K_; ++k) {
        const float4* c4 = (const float4*)(cp + (size_t)k * DT_);
        U c0u, c1u; c0u.f4 = c4[0]; c1u.f4 = c4[1];
        float da = 0.f, db = 0.f;
        #pragma unroll
        for (int i = 0; i < 8; ++i) {
            float cl0 = (float)c0u.h[i], cl1 = (float)c1u.h[i];
            da += av[i] * cl0 + av[8 + i] * cl1;
            db += bv[i] * cl0 + bv[8 + i] * cl1;
        }
        #pragma unroll
        for (int off = 32; off > 0; off >>= 1) {
            da += __shfl_down(da, off);
            db += __shfl_down(db, off);
        }
        if (lane == 0) {
            if (f0 < F_)     s_buf[((size_t)(bc * F_) + f0) * K_ + k] = da;
            if (f0 + 1 < F_) s_buf[((size_t)(bc * F_) + f0 + 1) * K_ + k] = db;
        }
    }
}

// ---------------------------------------------------------------------------
// 5. partial bap over f-segment, softmax stats computed inline per block
//    (online-softmax combine over 16 groups; redundant across NSEG blocks):
//    pp[seg][b][d] = sum_k cls[b,k,d] * sum_{f in seg} w[f,k]*v[bc,f,d]
__global__ __launch_bounds__(256)
void o_bap_partial(const __hip_bfloat16* __restrict__ v_buf,
                   const float* __restrict__ s_buf,
                   const __hip_bfloat16* __restrict__ cls,
                   float* __restrict__ pp, int b0) {
    int bc = blockIdx.x, seg = blockIdx.y;
    int b = b0 + bc;
    int t = threadIdx.x;
    int f0 = seg * FSEG;
    __shared__ float sm[16 * 16], sl[16 * 16];
    __shared__ float mk[K_], rlk[K_];
    {   // inline stats: thread (k = t&15, g = t>>4) scans f = g, g+16, ...
        int k = t & 15, g = t >> 4;
        float m = -INFINITY, l = 0.f;
        if (k < K_) {
            const float* sp = s_buf + (size_t)bc * F_ * K_ + k;
            for (int f = g; f < F_; f += 16) {
                float x = sp[(size_t)f * K_];
                if (x > m) { l = l * __expf(m - x) + 1.f; m = x; }
                else       { l += __expf(x - m); }
            }
            sm[k * 16 + g] = m; sl[k * 16 + g] = l;
        }
        __syncthreads();
        if (t < K_) {
            float M = -INFINITY, L = 0.f;
            for (int g2 = 0; g2 < 16; ++g2) {
                float mi = sm[t * 16 + g2], li = sl[t * 16 + g2];
                if (mi > M) { L = L * __expf(M - mi) + li; M = mi; }
                else        { L += li * __expf(mi - M); }
            }
            mk[t] = M; rlk[t] = 1.f / L;
        }
        __syncthreads();
    }
    __shared__ float wbuf[FSEG * K_];
    for (int j = t; j < FSEG * K_; j += 256) {
        int k = j % K_;
        float sv = s_buf[((size_t)bc * F_ + f0) * K_ + j];
        wbuf[j] = __expf(sv - mk[k]) * rlk[k];
    }
    __syncthreads();
    int d0 = t * 4;
    float acc[K_][4] = {};
    const __hip_bfloat16* vp = v_buf + ((size_t)bc * F_ + f0) * DT_ + d0;
    for (int f = 0; f < FSEG; ++f) {
        union { float2 f2; __hip_bfloat16 h[4]; } u;
        u.f2 = *(const float2*)(vp + (size_t)f * DT_);
        float vv[4];
        #pragma unroll
        for (int i = 0; i < 4; ++i) vv[i] = (float)u.h[i];
        const float* wk = &wbuf[f * K_];
        #pragma unroll
        for (int k = 0; k < K_; ++k)
            #pragma unroll
            for (int i = 0; i < 4; ++i) acc[k][i] += wk[k] * vv[i];
    }
    union { float2 f2; __hip_bfloat16 h[4]; } cu;
    float outv[4] = {};
    #pragma unroll
    for (int k = 0; k < K_; ++k) {
        cu.f2 = *(const float2*)(cls + ((size_t)b * K_ + k) * DT_ + d0);
        #pragma unroll
        for (int i = 0; i < 4; ++i) outv[i] += acc[k][i] * (float)cu.h[i];
    }
    float* pd = pp + ((size_t)seg * B_ + b) * DT_ + d0;
    *(float4*)pd = *(float4*)outv;
}

// 6b. combine segments -> bf16 bap
__global__ void bap_combine(const float* __restrict__ pp,
                            __hip_bfloat16* __restrict__ bap) {
    int idx = blockIdx.x * 256 + threadIdx.x;   // B_*DT_ total
    float s = pp[idx] + pp[idx + B_ * DT_] + pp[idx + 2 * B_ * DT_]
            + pp[idx + 3 * B_ * DT_];
    bap[idx] = (__hip_bfloat16)s;
}

// ---------------------------------------------------------------------------
// 7. zero out-row, then lg[b,k] = y[b,:] @ W_fc[:,k] + b_fc[k]; scatter.
__global__ void final_kernel(const float* __restrict__ y,
                             const float* __restrict__ Wfc,
                             const float* __restrict__ bfc,
                             const int* __restrict__ topk_idx,
                             float* __restrict__ out) {
    int b = blockIdx.x, tid = threadIdx.x;
    int lane = tid & 63, wave = tid >> 6;
    for (int i = tid; i < C_; i += 256) out[(size_t)b * C_ + i] = 0.f;
    float pk[K_] = {};
    for (int d = tid; d < DT_; d += 256) {
        float yv = y[(size_t)b * DT_ + d];
        #pragma unroll
        for (int k = 0; k < K_; ++k) pk[k] += yv * Wfc[(size_t)d * K_ + k];
    }
    __shared__ float wsum[4][K_];
    #pragma unroll
    for (int k = 0; k < K_; ++k) {
        float a = pk[k];
        #pragma unroll
        for (int off = 32; off > 0; off >>= 1) a += __shfl_down(a, off);
        if (lane == 0) wsum[wave][k] = a;
    }
    __syncthreads();   // also orders the zero-fill before the scatter below
    if (tid < K_) {
        float lg = wsum[0][tid] + wsum[1][tid] + wsum[2][tid] + wsum[3][tid] + bfc[tid];
        out[(size_t)b * C_ + topk_idx[b * K_ + tid]] = lg;
    }
}

// ---------------------------------------------------------------------------
extern "C" void kernel_launch(void* const* d_in, const int* in_sizes, int n_in,
                              void* d_out, int out_size, void* d_ws, size_t ws_size,
                              hipStream_t stream) {
    const float* ftm           = (const float*)d_in[0];
    const float* logits        = (const float*)d_in[1];
    const int*   indices_table = (const int*)d_in[3];
    const float* word2vec      = (const float*)d_in[4];
    const float* W_emb         = (const float*)d_in[5];
    const float* b_emb         = (const float*)d_in[6];
    const float* W_cls         = (const float*)d_in[7];
    const float* b_cls         = (const float*)d_in[8];
    const float* W_v           = (const float*)d_in[9];
    const float* b_v           = (const float*)d_in[10];
    const float* W_bap         = (const float*)d_in[11];
    const float* b_bap         = (const float*)d_in[12];
    const float* W_fc          = (const float*)d_in[13];
    const float* b_fc          = (const float*)d_in[14];
    float* out = (float*)d_out;

    char* ws = (char*)d_ws;
    size_t off = 0;
    auto alloc = [&](size_t bytes) -> void* {
        void* p = ws + off;
        off = (off + bytes + 255) & ~(size_t)255;
        return p;
    };
    int*            topk_idx = (int*)           alloc((size_t)B_ * K_ * 4);
    __hip_bfloat16* emb_bf   = (__hip_bfloat16*)alloc((size_t)B_ * K_ * DWP_ * 2);
    __hip_bfloat16* cls1     = (__hip_bfloat16*)alloc((size_t)B_ * K_ * DT_ * 2);
    __hip_bfloat16* cls2     = (__hip_bfloat16*)alloc((size_t)B_ * K_ * DT_ * 2);
    __hip_bfloat16* Wemb_t   = (__hip_bfloat16*)alloc((size_t)DT_ * DWP_ * 2);
    __hip_bfloat16* Wcls_t   = (__hip_bfloat16*)alloc((size_t)DT_ * DT_ * 2);
    __hip_bfloat16* Wv_t     = (__hip_bfloat16*)alloc((size_t)DT_ * DF_ * 2);
    __hip_bfloat16* Wbap_t   = (__hip_bfloat16*)alloc((size_t)DT_ * DT_ * 2);
    float*          s_buf    = (float*)         alloc((size_t)B_ * F_ * K_ * 4);
    float*          pp       = (float*)         alloc((size_t)NSEG * B_ * DT_ * 4);
    __hip_bfloat16* bap_bf   = (__hip_bfloat16*)alloc((size_t)B_ * DT_ * 2);
    float*          yb       = (float*)         alloc((size_t)B_ * DT_ * 4);

    // dynamic batch-chunk: fit ftm_t + v for nb batches in remaining ws
    size_t per_b = (size_t)F_ * DF_ * 2 + (size_t)F_ * DT_ * 2;
    size_t avail = (ws_size > off + 8192) ? ws_size - off - 8192 : 0;
    int nb = (int)(avail / per_b);
    if (nb > B_) nb = B_;
    if (nb < 1) nb = 1;
    __hip_bfloat16* ftm_t = (__hip_bfloat16*)alloc((size_t)nb * F_ * DF_ * 2);
    __hip_bfloat16* v_buf = (__hip_bfloat16*)alloc((size_t)nb * F_ * DT_ * 2);

    topk_emb_kernel<<<B_, 256, 0, stream>>>(logits, indices_table, word2vec,
                                            topk_idx, emb_bf);

    if (nb == B_) {
        // single-pass: all transposes in one dispatch
        transpose_all<<<784 + B_ * 132, 256, 0, stream>>>(
            W_emb, Wemb_t, W_cls, Wcls_t, W_v, Wv_t, W_bap, Wbap_t, ftm, ftm_t);
    } else {
        transpose_weights<<<784, 256, 0, stream>>>(
            W_emb, Wemb_t, W_cls, Wcls_t, W_v, Wv_t, W_bap, Wbap_t);
    }

    // cls path (MFMA); M = 640 = 5*128 exact
    gemm_mfma<1, 1, 0><<<dim3(DT_ / 128, 5), 256, 0, stream>>>(
        emb_bf, Wemb_t, b_emb, cls1, B_ * K_, DT_, DWP_);
    gemm_mfma<1, 1, 0><<<dim3(DT_ / 128, 5), 256, 0, stream>>>(
        cls1, Wcls_t, b_cls, cls2, B_ * K_, DT_, DT_);

    // main path, chunked only if ws is small (nb == 64 -> single pass)
    for (int b0 = 0; b0 < B_; b0 += nb) {
        int cb = min(nb, B_ - b0);
        if (nb != B_) {
            transpose_ftm<<<dim3(11, 12, cb), 256, 0, stream>>>(
                ftm + (size_t)b0 * DF_ * F_, ftm_t);
        }
        int M = cb * F_;
        int mblocks = (M + 127) / 128;
        int mb_pad = (mblocks + 7) & ~7;
        gemm_mfma<1, 1, 1><<<dim3(8, mb_pad), 256, 0, stream>>>(
            ftm_t, Wv_t, b_v, v_buf, M, DT_, DF_);
        float* s_c = s_buf + (size_t)b0 * F_ * K_;
        attn_s_kernel<<<dim3((F_ + 7) / 8, cb), 256, 0, stream>>>(
            v_buf, cls2, s_c, b0);
        o_bap_partial<<<dim3(cb, NSEG), 256, 0, stream>>>(
            v_buf, s_c, cls2, pp, b0);
    }
    bap_combine<<<B_ * DT_ / 256, 256, 0, stream>>>(pp, bap_bf);

    gemm_mfma<1, 0, 0><<<dim3(DT_ / 128, 1), 256, 0, stream>>>(
        bap_bf, Wbap_t, b_bap, yb, B_, DT_, DT_);
    final_kernel<<<B_, 256, 0, stream>>>(yb, W_fc, b_fc, topk_idx, out);
}